// Round 1
// baseline (2997.369 us; speedup 1.0000x reference)
//
#include <hip/hip_runtime.h>
#include <hip/hip_bf16.h>
#include <math.h>

#define DIM_  1536
#define NH_   12
#define HD_   128
#define S_    2048
#define B_    2
#define M_    (B_*S_)   /* 4096 rows */

// ---------------------------------------------------------------------------
// Generic fp32 GEMM: Out[M,N] = X[M,K] @ W[N,K]^T + bias[N]
// 64x64 tile, BK=16, 256 threads, 4x4 micro-tile per thread.
// ---------------------------------------------------------------------------
__global__ __launch_bounds__(256) void gemm_bias_k(
    const float* __restrict__ X, const float* __restrict__ W,
    const float* __restrict__ bias, float* __restrict__ Out,
    int M, int N, int K)
{
  __shared__ float Xs[16][68];
  __shared__ float Ws[16][68];
  const int t  = threadIdx.x;
  const int m0 = blockIdx.y * 64;
  const int n0 = blockIdx.x * 64;
  const int rm = (t >> 4) << 2;
  const int rn = (t & 15) << 2;
  float acc[4][4] = {};
  for (int k0 = 0; k0 < K; k0 += 16) {
#pragma unroll
    for (int i = 0; i < 4; ++i) {
      int e  = t + i * 256;
      int kk = e & 15;
      int mm = e >> 4;
      Xs[kk][mm] = X[(size_t)(m0 + mm) * K + k0 + kk];
      Ws[kk][mm] = W[(size_t)(n0 + mm) * K + k0 + kk];
    }
    __syncthreads();
#pragma unroll
    for (int kk = 0; kk < 16; ++kk) {
      float4 a = *reinterpret_cast<const float4*>(&Xs[kk][rm]);
      float4 b = *reinterpret_cast<const float4*>(&Ws[kk][rn]);
      float av[4] = {a.x, a.y, a.z, a.w};
      float bv[4] = {b.x, b.y, b.z, b.w};
#pragma unroll
      for (int i = 0; i < 4; ++i)
#pragma unroll
        for (int j = 0; j < 4; ++j)
          acc[i][j] = fmaf(av[i], bv[j], acc[i][j]);
    }
    __syncthreads();
  }
#pragma unroll
  for (int i = 0; i < 4; ++i)
#pragma unroll
    for (int j = 0; j < 4; ++j) {
      size_t off = (size_t)(m0 + rm + i) * N + (n0 + rn + j);
      Out[off] = acc[i][j] + bias[n0 + rn + j];
    }
}

// ---------------------------------------------------------------------------
// Fused RMSNorm (over full DIM) + grid RoPE, in place. One block per row.
// t layout: [B*S, DIM] viewed as [B*S, NH, 64 pairs, 2]
// ---------------------------------------------------------------------------
__global__ __launch_bounds__(256) void rms_rope_k(
    float* __restrict__ t, const float* __restrict__ w,
    const float* __restrict__ cf, const float* __restrict__ sf,
    const float* __restrict__ ch, const float* __restrict__ sh,
    const float* __restrict__ cw, const float* __restrict__ sw)
{
  const int row = blockIdx.x;          // b*S + s
  const int s   = row & (S_ - 1);
  float* rp = t + (size_t)row * DIM_;

  float ss = 0.f;
  for (int i = threadIdx.x; i < DIM_; i += 256) {
    float v = rp[i];
    ss += v * v;
  }
#pragma unroll
  for (int off = 32; off > 0; off >>= 1) ss += __shfl_down(ss, off);
  __shared__ float red[4];
  if ((threadIdx.x & 63) == 0) red[threadIdx.x >> 6] = ss;
  __syncthreads();
  float tot   = red[0] + red[1] + red[2] + red[3];
  float scale = rsqrtf(tot * (1.0f / DIM_) + 1e-6f);

  const int fi = s >> 8;          // s / 256
  const int hi = (s >> 4) & 15;
  const int wi = s & 15;

  for (int p = threadIdx.x; p < NH_ * 64; p += 256) {
    int n = p >> 6;
    int c = p & 63;
    float co, si;
    if (c < 22)      { co = cf[fi * 22 + c];        si = sf[fi * 22 + c]; }
    else if (c < 43) { co = ch[hi * 21 + (c - 22)]; si = sh[hi * 21 + (c - 22)]; }
    else             { co = cw[wi * 21 + (c - 43)]; si = sw[wi * 21 + (c - 43)]; }
    int d0 = n * HD_ + 2 * c;
    float xr = rp[d0]     * scale * w[d0];
    float xi = rp[d0 + 1] * scale * w[d0 + 1];
    rp[d0]     = xr * co - xi * si;
    rp[d0 + 1] = xr * si + xi * co;
  }
}

// ---------------------------------------------------------------------------
// fp32 flash attention. Block = 256 threads = one (b, h, 32-query tile).
// Thread (r = tid/8, sub = tid%8) owns dims [sub*16, sub*16+16) of row r.
// K/V staged in LDS in 32-key chunks; online softmax; ragged kv_len by
// looping only ceil(kvlen/32) chunks.
// ---------------------------------------------------------------------------
__global__ __launch_bounds__(256) void attn_k(
    const float* __restrict__ q, const float* __restrict__ k,
    const float* __restrict__ v, const int* __restrict__ seq_lens,
    float* __restrict__ o)
{
  const int bh = blockIdx.y;            // b*NH + h
  const int b  = bh / NH_;
  const int h  = bh - b * NH_;
  const int q0 = blockIdx.x << 5;       // 32 queries per block
  const int kvlen = seq_lens[b];
  const int tid = threadIdx.x;
  const int r   = tid >> 3;
  const int sub = tid & 7;

  __shared__ float Kc[32][128];
  __shared__ float Vc[32][128];
  __shared__ float sc[32][32];

  const size_t qbase = ((size_t)(b * S_ + q0 + r) * NH_ + h) * HD_ + sub * 16;
  float qf[16];
#pragma unroll
  for (int i = 0; i < 16; i += 4) {
    float4 t4 = *reinterpret_cast<const float4*>(q + qbase + i);
    qf[i] = t4.x; qf[i + 1] = t4.y; qf[i + 2] = t4.z; qf[i + 3] = t4.w;
  }

  float oacc[16] = {};
  float m = -1e30f, l = 0.f;
  const float sscale = 0.08838834764831845f;   // 1/sqrt(128)

  const int nch = (kvlen + 31) >> 5;
  for (int c0 = 0; c0 < nch; ++c0) {
    const int kk0 = c0 << 5;
    // stage K/V chunk: 32 keys x 128 dims, float4 per thread x4
#pragma unroll
    for (int i2 = 0; i2 < 4; ++i2) {
      int f  = tid + i2 * 256;           // float4 index, 0..1023
      int j  = f >> 5;
      int d4 = f & 31;
      size_t g = ((size_t)(b * S_ + kk0 + j) * NH_ + h) * HD_ + d4 * 4;
      *reinterpret_cast<float4*>(&Kc[j][d4 * 4]) =
          *reinterpret_cast<const float4*>(k + g);
      *reinterpret_cast<float4*>(&Vc[j][d4 * 4]) =
          *reinterpret_cast<const float4*>(v + g);
    }
    __syncthreads();

    // scores: each (r,sub) does 16-dim partials, butterfly over 8 subs
    for (int j = 0; j < 32; ++j) {
      float p = 0.f;
#pragma unroll
      for (int i = 0; i < 16; ++i) p = fmaf(qf[i], Kc[j][sub * 16 + i], p);
      p += __shfl_xor(p, 1);
      p += __shfl_xor(p, 2);
      p += __shfl_xor(p, 4);
      if (sub == 0) {
        int kkj = kk0 + j;
        sc[r][j] = (kkj < kvlen) ? p * sscale : -1e30f;
      }
    }
    __syncthreads();

    // online softmax update (each of the 8 subs per row redundantly)
    float cmax = -1e30f;
    for (int j = 0; j < 32; ++j) cmax = fmaxf(cmax, sc[r][j]);
    float mnew  = fmaxf(m, cmax);
    float alpha = __expf(m - mnew);
    l *= alpha;
#pragma unroll
    for (int i = 0; i < 16; ++i) oacc[i] *= alpha;
    for (int j = 0; j < 32; ++j) {
      float p = __expf(sc[r][j] - mnew);
      l += p;
#pragma unroll
      for (int i = 0; i < 16; ++i)
        oacc[i] = fmaf(p, Vc[j][sub * 16 + i], oacc[i]);
    }
    m = mnew;
    __syncthreads();
  }

  const float inv_l = 1.f / l;
  const size_t ob = ((size_t)(b * S_ + q0 + r) * NH_ + h) * HD_ + sub * 16;
#pragma unroll
  for (int i = 0; i < 16; i += 4) {
    float4 t4;
    t4.x = oacc[i] * inv_l;   t4.y = oacc[i + 1] * inv_l;
    t4.z = oacc[i + 2] * inv_l; t4.w = oacc[i + 3] * inv_l;
    *reinterpret_cast<float4*>(o + ob + i) = t4;
  }
}

// ---------------------------------------------------------------------------
extern "C" void kernel_launch(void* const* d_in, const int* in_sizes, int n_in,
                              void* d_out, int out_size, void* d_ws, size_t ws_size,
                              hipStream_t stream) {
  const float* x        = (const float*)d_in[0];
  const int*   seq_lens = (const int*)d_in[1];
  // d_in[2..4] = f,h,w scalars (hard-coded 8,16,16)
  const float* wq = (const float*)d_in[5];
  const float* bq = (const float*)d_in[6];
  const float* wk = (const float*)d_in[7];
  const float* bk = (const float*)d_in[8];
  const float* wv = (const float*)d_in[9];
  const float* bv = (const float*)d_in[10];
  const float* wo = (const float*)d_in[11];
  const float* bo = (const float*)d_in[12];
  const float* nq = (const float*)d_in[13];
  const float* nk = (const float*)d_in[14];
  const float* cf = (const float*)d_in[15];
  const float* sf = (const float*)d_in[16];
  const float* ch = (const float*)d_in[17];
  const float* sh = (const float*)d_in[18];
  const float* cw = (const float*)d_in[19];
  const float* sw = (const float*)d_in[20];

  const size_t rowelems = (size_t)M_ * DIM_;      // 6291456
  float* q   = (float*)d_ws;
  float* k   = q + rowelems;
  float* v   = k + rowelems;
  float* att = v + rowelems;
  float* out = (float*)d_out;

  dim3 gg(DIM_ / 64, M_ / 64);   // (24, 64)
  gemm_bias_k<<<gg, 256, 0, stream>>>(x, wq, bq, q, M_, DIM_, DIM_);
  gemm_bias_k<<<gg, 256, 0, stream>>>(x, wk, bk, k, M_, DIM_, DIM_);
  gemm_bias_k<<<gg, 256, 0, stream>>>(x, wv, bv, v, M_, DIM_, DIM_);

  rms_rope_k<<<M_, 256, 0, stream>>>(q, nq, cf, sf, ch, sh, cw, sw);
  rms_rope_k<<<M_, 256, 0, stream>>>(k, nk, cf, sf, ch, sh, cw, sw);

  attn_k<<<dim3(S_ / 32, B_ * NH_), 256, 0, stream>>>(q, k, v, seq_lens, att);

  gemm_bias_k<<<gg, 256, 0, stream>>>(att, wo, bo, out, M_, DIM_, DIM_);
}

// Round 2
// 1392.624 us; speedup vs baseline: 2.1523x; 2.1523x over previous
//
#include <hip/hip_runtime.h>
#include <hip/hip_bf16.h>
#include <math.h>

#define DIM_  1536
#define NH_   12
#define HD_   128
#define S_    2048
#define B_    2
#define M_    (B_*S_)   /* 4096 rows */

typedef __attribute__((ext_vector_type(8))) short bf16x8;
typedef __attribute__((ext_vector_type(4))) short short4v;
typedef __attribute__((ext_vector_type(4))) float f32x4;

static __device__ __forceinline__ short f2bf(float f) {
  union { __hip_bfloat16 h; short s; } u;
  u.h = __float2bfloat16(f);
  return u.s;
}

// ---------------------------------------------------------------------------
// Generic fp32 GEMM: Out[M,N] = X[M,K] @ W[N,K]^T + bias[N]
// ---------------------------------------------------------------------------
__global__ __launch_bounds__(256) void gemm_bias_k(
    const float* __restrict__ X, const float* __restrict__ W,
    const float* __restrict__ bias, float* __restrict__ Out,
    int M, int N, int K)
{
  __shared__ float Xs[16][68];
  __shared__ float Ws[16][68];
  const int t  = threadIdx.x;
  const int m0 = blockIdx.y * 64;
  const int n0 = blockIdx.x * 64;
  const int rm = (t >> 4) << 2;
  const int rn = (t & 15) << 2;
  float acc[4][4] = {};
  for (int k0 = 0; k0 < K; k0 += 16) {
#pragma unroll
    for (int i = 0; i < 4; ++i) {
      int e  = t + i * 256;
      int kk = e & 15;
      int mm = e >> 4;
      Xs[kk][mm] = X[(size_t)(m0 + mm) * K + k0 + kk];
      Ws[kk][mm] = W[(size_t)(n0 + mm) * K + k0 + kk];
    }
    __syncthreads();
#pragma unroll
    for (int kk = 0; kk < 16; ++kk) {
      float4 a = *reinterpret_cast<const float4*>(&Xs[kk][rm]);
      float4 b = *reinterpret_cast<const float4*>(&Ws[kk][rn]);
      float av[4] = {a.x, a.y, a.z, a.w};
      float bv[4] = {b.x, b.y, b.z, b.w};
#pragma unroll
      for (int i = 0; i < 4; ++i)
#pragma unroll
        for (int j = 0; j < 4; ++j)
          acc[i][j] = fmaf(av[i], bv[j], acc[i][j]);
    }
    __syncthreads();
  }
#pragma unroll
  for (int i = 0; i < 4; ++i)
#pragma unroll
    for (int j = 0; j < 4; ++j) {
      size_t off = (size_t)(m0 + rm + i) * N + (n0 + rn + j);
      Out[off] = acc[i][j] + bias[n0 + rn + j];
    }
}

// ---------------------------------------------------------------------------
// RMSNorm (full DIM) + grid RoPE, reading fp32 [b*S+s][DIM], writing bf16
// head-major [b][h][s][d]. One block per row.
// ---------------------------------------------------------------------------
__global__ __launch_bounds__(256) void rms_rope_pack_k(
    const float* __restrict__ t, const float* __restrict__ w,
    const float* __restrict__ cf, const float* __restrict__ sf,
    const float* __restrict__ ch, const float* __restrict__ sh,
    const float* __restrict__ cw, const float* __restrict__ sw,
    short* __restrict__ outb)
{
  const int row = blockIdx.x;
  const int b   = row >> 11;
  const int s   = row & (S_ - 1);
  const float* rp = t + (size_t)row * DIM_;

  float ss = 0.f;
  for (int i = threadIdx.x; i < DIM_; i += 256) { float v2 = rp[i]; ss += v2 * v2; }
#pragma unroll
  for (int off = 32; off > 0; off >>= 1) ss += __shfl_down(ss, off);
  __shared__ float red[4];
  if ((threadIdx.x & 63) == 0) red[threadIdx.x >> 6] = ss;
  __syncthreads();
  float scale = rsqrtf((red[0] + red[1] + red[2] + red[3]) * (1.f / DIM_) + 1e-6f);

  const int fi = s >> 8;
  const int hi = (s >> 4) & 15;
  const int wi = s & 15;

  for (int p = threadIdx.x; p < NH_ * 64; p += 256) {
    int n = p >> 6, c = p & 63;
    float co, si;
    if (c < 22)      { co = cf[fi * 22 + c];        si = sf[fi * 22 + c]; }
    else if (c < 43) { co = ch[hi * 21 + (c - 22)]; si = sh[hi * 21 + (c - 22)]; }
    else             { co = cw[wi * 21 + (c - 43)]; si = sw[wi * 21 + (c - 43)]; }
    int d0 = n * HD_ + 2 * c;
    float xr = rp[d0]     * scale * w[d0];
    float xi = rp[d0 + 1] * scale * w[d0 + 1];
    float rr = xr * co - xi * si;
    float ri = xr * si + xi * co;
    unsigned int pk = (unsigned int)(unsigned short)f2bf(rr)
                    | ((unsigned int)(unsigned short)f2bf(ri) << 16);
    *(unsigned int*)(outb + (((size_t)(b * NH_ + n) * S_ + s) * HD_ + 2 * c)) = pk;
  }
}

// ---------------------------------------------------------------------------
// V transpose: fp32 [b*S+s][h*128+d]  ->  bf16 [b][h][d][s]
// One block per (64 s) x (128 d) tile of one (b,h).
// ---------------------------------------------------------------------------
__global__ __launch_bounds__(256) void v_transpose_k(
    const float* __restrict__ v, short* __restrict__ vtb)
{
  const int bh = blockIdx.y;
  const int b  = bh / NH_;
  const int h  = bh - b * NH_;
  const int s0 = blockIdx.x << 6;
  __shared__ short tile[64][130];
  const int tid = threadIdx.x;
#pragma unroll
  for (int i = 0; i < 8; ++i) {
    int f  = tid + (i << 8);           // 0..2047
    int sl = f >> 5, d4 = f & 31;
    float4 t4 = *(const float4*)(v + (size_t)(b * S_ + s0 + sl) * DIM_ + h * 128 + d4 * 4);
    tile[sl][d4 * 4 + 0] = f2bf(t4.x);
    tile[sl][d4 * 4 + 1] = f2bf(t4.y);
    tile[sl][d4 * 4 + 2] = f2bf(t4.z);
    tile[sl][d4 * 4 + 3] = f2bf(t4.w);
  }
  __syncthreads();
#pragma unroll
  for (int i = 0; i < 8; ++i) {
    int f  = tid + (i << 8);           // 0..2047
    int d  = f >> 4, s4 = f & 15;
    short4v o4;
    o4[0] = tile[s4 * 4 + 0][d];
    o4[1] = tile[s4 * 4 + 1][d];
    o4[2] = tile[s4 * 4 + 2][d];
    o4[3] = tile[s4 * 4 + 3][d];
    *(short4v*)(vtb + ((size_t)bh * HD_ + d) * S_ + s0 + s4 * 4) = o4;
  }
}

// ---------------------------------------------------------------------------
// bf16 MFMA flash attention. Block = 4 waves; wave w owns queries
// q0+16w..q0+16w+15 of one (b,h). 64-key tiles staged in swizzled LDS.
// kvlens are multiples of 64 -> no key masking needed.
// ---------------------------------------------------------------------------
__global__ __launch_bounds__(256) void attn_mfma_k(
    const short* __restrict__ qb, const short* __restrict__ kb,
    const short* __restrict__ vtb, const int* __restrict__ seq_lens,
    float* __restrict__ o)
{
  const int bh = blockIdx.y;
  const int b  = bh / NH_;
  const int h  = bh - b * NH_;
  const int q0 = blockIdx.x << 6;
  const int kvlen = seq_lens[b];
  const int tid  = threadIdx.x;
  const int wid  = tid >> 6;
  const int lane = tid & 63;
  const int lg   = lane >> 4;
  const int lc   = lane & 15;

  __shared__ __align__(16) short Kt[64 * 128];
  __shared__ __align__(16) short Vt[128 * 64];
  __shared__ __align__(16) short Pt[4][16 * 64];

  // Q fragments: A-layout row = lane&15 (query), k = 8*(lane>>4)+i (dim)
  bf16x8 aq[4];
  {
    const size_t base = ((size_t)bh * S_ + q0 + wid * 16 + lc) * HD_;
#pragma unroll
    for (int kc = 0; kc < 4; ++kc)
      aq[kc] = *reinterpret_cast<const bf16x8*>(qb + base + kc * 32 + lg * 8);
  }

  f32x4 oacc[8] = {};
  float mrow[4], lrow[4];
#pragma unroll
  for (int r = 0; r < 4; ++r) { mrow[r] = -3.0e38f; lrow[r] = 0.f; }

  const float c_log2 = 0.08838834764831845f * 1.4426950408889634f; // scale*log2e

  char* kbase = (char*)Kt;
  char* vbase = (char*)Vt;
  char* pbase = (char*)(&Pt[wid][0]);

  const int nt = kvlen >> 6;
  for (int t0 = 0; t0 < nt; ++t0) {
    const int k0 = t0 << 6;
    __syncthreads();
    // stage K: 64 keys x 128 dims, swizzled rows of 256B
#pragma unroll
    for (int i = 0; i < 4; ++i) {
      int c2  = tid + (i << 8);
      int row = c2 >> 4, col = c2 & 15;
      bf16x8 val = *reinterpret_cast<const bf16x8*>(
          kb + ((size_t)bh * S_ + k0 + row) * HD_ + col * 8);
      *reinterpret_cast<bf16x8*>(kbase + row * 256 + ((col * 16) ^ ((row & 7) << 4))) = val;
    }
    // stage V^T: 128 dims x 64 keys, swizzled rows of 128B
#pragma unroll
    for (int i = 0; i < 4; ++i) {
      int c2  = tid + (i << 8);
      int row = c2 >> 3, col = c2 & 7;
      bf16x8 val = *reinterpret_cast<const bf16x8*>(
          vtb + ((size_t)bh * HD_ + row) * S_ + k0 + col * 8);
      *reinterpret_cast<bf16x8*>(vbase + row * 128 + ((col * 16) ^ ((row & 7) << 4))) = val;
    }
    __syncthreads();

    // QK^T: S[16 q][64 k] in 4 n-tiles
    f32x4 sacc[4];
#pragma unroll
    for (int n = 0; n < 4; ++n) {
      f32x4 acc = {0.f, 0.f, 0.f, 0.f};
      int krow = n * 16 + lc;
#pragma unroll
      for (int kc = 0; kc < 4; ++kc) {
        bf16x8 bk = *reinterpret_cast<const bf16x8*>(
            kbase + krow * 256 + ((kc * 64 + lg * 16) ^ ((krow & 7) << 4)));
        acc = __builtin_amdgcn_mfma_f32_16x16x32_bf16(aq[kc], bk, acc, 0, 0, 0);
      }
      sacc[n] = acc;
    }

    // online softmax; D row = 4*lg + r, col = lc
#pragma unroll
    for (int r = 0; r < 4; ++r) {
      float s0v = sacc[0][r] * c_log2;
      float s1v = sacc[1][r] * c_log2;
      float s2v = sacc[2][r] * c_log2;
      float s3v = sacc[3][r] * c_log2;
      float mx = fmaxf(fmaxf(s0v, s1v), fmaxf(s2v, s3v));
      mx = fmaxf(mx, __shfl_xor(mx, 1));
      mx = fmaxf(mx, __shfl_xor(mx, 2));
      mx = fmaxf(mx, __shfl_xor(mx, 4));
      mx = fmaxf(mx, __shfl_xor(mx, 8));
      float mnew  = fmaxf(mrow[r], mx);
      float alpha = exp2f(mrow[r] - mnew);
      mrow[r] = mnew;
      float p0 = exp2f(s0v - mnew);
      float p1 = exp2f(s1v - mnew);
      float p2 = exp2f(s2v - mnew);
      float p3 = exp2f(s3v - mnew);
      float ls = p0 + p1 + p2 + p3;
      ls += __shfl_xor(ls, 1);
      ls += __shfl_xor(ls, 2);
      ls += __shfl_xor(ls, 4);
      ls += __shfl_xor(ls, 8);
      lrow[r] = lrow[r] * alpha + ls;
#pragma unroll
      for (int n2 = 0; n2 < 8; ++n2) oacc[n2][r] *= alpha;
      int qr = 4 * lg + r;
      int xo = (qr & 7) << 4;
      *(short*)(pbase + qr * 128 + (((0 * 16 + lc) * 2) ^ xo)) = f2bf(p0);
      *(short*)(pbase + qr * 128 + (((1 * 16 + lc) * 2) ^ xo)) = f2bf(p1);
      *(short*)(pbase + qr * 128 + (((2 * 16 + lc) * 2) ^ xo)) = f2bf(p2);
      *(short*)(pbase + qr * 128 + (((3 * 16 + lc) * 2) ^ xo)) = f2bf(p3);
    }
    asm volatile("s_waitcnt lgkmcnt(0)" ::: "memory");
    __builtin_amdgcn_sched_barrier(0);

    // PV: O[16 q][128 d] += P[16 q][64 k] @ V[64 k][128 d]
#pragma unroll
    for (int kc2 = 0; kc2 < 2; ++kc2) {
      bf16x8 ap = *reinterpret_cast<const bf16x8*>(
          pbase + lc * 128 + ((kc2 * 64 + lg * 16) ^ ((lc & 7) << 4)));
#pragma unroll
      for (int n = 0; n < 8; ++n) {
        int vrow = n * 16 + lc;
        bf16x8 bv = *reinterpret_cast<const bf16x8*>(
            vbase + vrow * 128 + ((kc2 * 64 + lg * 16) ^ ((vrow & 7) << 4)));
        oacc[n] = __builtin_amdgcn_mfma_f32_16x16x32_bf16(ap, bv, oacc[n], 0, 0, 0);
      }
    }
  }

  float inv[4];
#pragma unroll
  for (int r = 0; r < 4; ++r) inv[r] = 1.f / lrow[r];
#pragma unroll
  for (int n = 0; n < 8; ++n) {
#pragma unroll
    for (int r = 0; r < 4; ++r) {
      int qrow = q0 + wid * 16 + 4 * lg + r;
      o[((size_t)(b * S_ + qrow) * NH_ + h) * HD_ + n * 16 + lc] = oacc[n][r] * inv[r];
    }
  }
}

// ---------------------------------------------------------------------------
extern "C" void kernel_launch(void* const* d_in, const int* in_sizes, int n_in,
                              void* d_out, int out_size, void* d_ws, size_t ws_size,
                              hipStream_t stream) {
  const float* x        = (const float*)d_in[0];
  const int*   seq_lens = (const int*)d_in[1];
  const float* wq = (const float*)d_in[5];
  const float* bq = (const float*)d_in[6];
  const float* wk = (const float*)d_in[7];
  const float* bk = (const float*)d_in[8];
  const float* wv = (const float*)d_in[9];
  const float* bv = (const float*)d_in[10];
  const float* wo = (const float*)d_in[11];
  const float* bo = (const float*)d_in[12];
  const float* nq = (const float*)d_in[13];
  const float* nk = (const float*)d_in[14];
  const float* cf = (const float*)d_in[15];
  const float* sf = (const float*)d_in[16];
  const float* ch = (const float*)d_in[17];
  const float* sh = (const float*)d_in[18];
  const float* cw = (const float*)d_in[19];
  const float* sw = (const float*)d_in[20];

  const size_t rowelems = (size_t)M_ * DIM_;          // 6291456
  float* qf = (float*)d_ws;                            // 25.2 MB
  float* kf = qf + rowelems;                           // 25.2 MB
  float* vf = kf + rowelems;                           // 25.2 MB
  short* qb = (short*)(vf + rowelems);                 // 12.6 MB bf16 head-major
  short* kb = qb + rowelems;                           // 12.6 MB
  short* vtb = (short*)kf;      // aliases dead k-fp32 after rms_rope(k)
  float* att = qf;              // aliases dead q-fp32 after rms_rope(q)
  float* out = (float*)d_out;

  dim3 gg(DIM_ / 64, M_ / 64);   // (24, 64)
  gemm_bias_k<<<gg, 256, 0, stream>>>(x, wq, bq, qf, M_, DIM_, DIM_);
  gemm_bias_k<<<gg, 256, 0, stream>>>(x, wk, bk, kf, M_, DIM_, DIM_);
  gemm_bias_k<<<gg, 256, 0, stream>>>(x, wv, bv, vf, M_, DIM_, DIM_);

  rms_rope_pack_k<<<M_, 256, 0, stream>>>(qf, nq, cf, sf, ch, sh, cw, sw, qb);
  rms_rope_pack_k<<<M_, 256, 0, stream>>>(kf, nk, cf, sf, ch, sh, cw, sw, kb);
  v_transpose_k<<<dim3(S_ / 64, B_ * NH_), 256, 0, stream>>>(vf, vtb);

  attn_mfma_k<<<dim3(S_ / 64, B_ * NH_), 256, 0, stream>>>(qb, kb, vtb, seq_lens, att);

  gemm_bias_k<<<gg, 256, 0, stream>>>(att, wo, bo, out, M_, DIM_, DIM_);
}

// Round 3
// 436.647 us; speedup vs baseline: 6.8645x; 3.1894x over previous
//
#include <hip/hip_runtime.h>
#include <hip/hip_bf16.h>
#include <math.h>

#define DIM_  1536
#define NH_   12
#define HD_   128
#define S_    2048
#define B_    2
#define M_    (B_*S_)   /* 4096 rows */

typedef __attribute__((ext_vector_type(8))) _Float16 f16x8;
typedef __attribute__((ext_vector_type(4))) short short4v;
typedef __attribute__((ext_vector_type(8))) short short8v;
typedef __attribute__((ext_vector_type(4))) float f32x4;

static __device__ __forceinline__ short f2h(float f) {
  union { _Float16 h; short s; } u;
  u.h = (_Float16)f;
  return u.s;
}

// ---------------------------------------------------------------------------
// fp32 -> fp16 pack, 8 elems/thread
// ---------------------------------------------------------------------------
__global__ __launch_bounds__(256) void f2h_k(
    const float* __restrict__ in, short* __restrict__ out, int n8)
{
  int i = blockIdx.x * 256 + threadIdx.x;
  if (i >= n8) return;
  const float4* p = (const float4*)in + (size_t)i * 2;
  float4 a = p[0], b = p[1];
  short8v o;
  o[0] = f2h(a.x); o[1] = f2h(a.y); o[2] = f2h(a.z); o[3] = f2h(a.w);
  o[4] = f2h(b.x); o[5] = f2h(b.y); o[6] = f2h(b.z); o[7] = f2h(b.w);
  *((short8v*)out + i) = o;
}

// ---------------------------------------------------------------------------
// MFMA fp16 GEMM core: Out[4096,1536] = A16[4096,1536] @ W[1536,1536]^T + bias
// 128x128 tile, BK=32, 4 waves (2x2), A via global_load_lds (pre-swizzled
// source), B (fp32) converted in-reg and ds_write'd swizzled.
// Swizzle: 16B slot s of row r stored at s ^ ((r>>1)&3)  -> conflict-free
// ds_read_b128 fragments.
// ---------------------------------------------------------------------------
static __device__ __forceinline__ void gemm128_core(
    const short* __restrict__ A16, const float* __restrict__ W,
    const float* __restrict__ bias, float* __restrict__ Out,
    int m0, int n0)
{
  __shared__ __align__(16) char Atile[8192];
  __shared__ __align__(16) char Btile[8192];
  const int tid = threadIdx.x;
  const int l  = tid & 63, w = tid >> 6;
  const int wr = w >> 1, wc = w & 1;
  const int lc = l & 15, lg = l >> 4;

  f32x4 acc[4][4] = {};

  for (int k0 = 0; k0 < DIM_; k0 += 32) {
    // ---- stage A (fp16 in global): 2 x global_load_lds_dwordx4 per thread-pass
#pragma unroll
    for (int i = 0; i < 2; ++i) {
      int row   = i * 64 + w * 16 + (l >> 2);
      int slot  = l & 3;
      int gslot = slot ^ ((row >> 1) & 3);
      const short* g = A16 + (size_t)(m0 + row) * DIM_ + k0 + gslot * 8;
      __builtin_amdgcn_global_load_lds(
          (const __attribute__((address_space(1))) unsigned*)g,
          (__attribute__((address_space(3))) unsigned*)(Atile + i * 4096 + w * 1024),
          16, 0, 0);
    }
    // ---- stage B (fp32 weights -> fp16, swizzled ds_write_b64)
#pragma unroll
    for (int i = 0; i < 4; ++i) {
      int e   = tid + i * 256;        // float4 unit, 0..1023
      int row = e >> 3, f4 = e & 7;
      float4 v4 = *(const float4*)(W + (size_t)(n0 + row) * DIM_ + k0 + f4 * 4);
      short4v h4;
      h4[0] = f2h(v4.x); h4[1] = f2h(v4.y); h4[2] = f2h(v4.z); h4[3] = f2h(v4.w);
      int slot = f4 >> 1;
      *(short4v*)(Btile + row * 64 + (((slot ^ ((row >> 1) & 3)) << 4)) + ((f4 & 1) << 3)) = h4;
    }
    __syncthreads();

    // ---- fragments + 16 MFMA
    f16x8 af[4], bf[4];
#pragma unroll
    for (int mt = 0; mt < 4; ++mt) {
      int ar = wr * 64 + mt * 16 + lc;
      af[mt] = *(const f16x8*)(Atile + ar * 64 + ((lg ^ ((ar >> 1) & 3)) << 4));
    }
#pragma unroll
    for (int nt = 0; nt < 4; ++nt) {
      int br = wc * 64 + nt * 16 + lc;
      bf[nt] = *(const f16x8*)(Btile + br * 64 + ((lg ^ ((br >> 1) & 3)) << 4));
    }
#pragma unroll
    for (int mt = 0; mt < 4; ++mt)
#pragma unroll
      for (int nt = 0; nt < 4; ++nt)
        acc[mt][nt] = __builtin_amdgcn_mfma_f32_16x16x32_f16(af[mt], bf[nt], acc[mt][nt], 0, 0, 0);
    __syncthreads();
  }

  // ---- epilogue: bias + fp32 store (D: col=lc, row=lg*4+r)
#pragma unroll
  for (int nt = 0; nt < 4; ++nt) {
    int col = n0 + wc * 64 + nt * 16 + lc;
    float bb = bias[col];
#pragma unroll
    for (int mt = 0; mt < 4; ++mt) {
#pragma unroll
      for (int r = 0; r < 4; ++r) {
        int rowm = m0 + wr * 64 + mt * 16 + lg * 4 + r;
        Out[(size_t)rowm * DIM_ + col] = acc[mt][nt][r] + bb;
      }
    }
  }
}

__global__ __launch_bounds__(256) void gemm_qkv_k(
    const short* __restrict__ x16,
    const float* __restrict__ wq, const float* __restrict__ wk, const float* __restrict__ wv,
    const float* __restrict__ bq, const float* __restrict__ bk, const float* __restrict__ bv,
    float* __restrict__ qf, float* __restrict__ kf, float* __restrict__ vf)
{
  const int z = blockIdx.z;
  const float* W  = (z == 0) ? wq : (z == 1) ? wk : wv;
  const float* bi = (z == 0) ? bq : (z == 1) ? bk : bv;
  float*       O  = (z == 0) ? qf : (z == 1) ? kf : vf;
  gemm128_core(x16, W, bi, O, blockIdx.y * 128, blockIdx.x * 128);
}

__global__ __launch_bounds__(256) void gemm_out_k(
    const short* __restrict__ att16, const float* __restrict__ wo,
    const float* __restrict__ bo, float* __restrict__ out)
{
  gemm128_core(att16, wo, bo, out, blockIdx.y * 128, blockIdx.x * 128);
}

// ---------------------------------------------------------------------------
// RMSNorm (full DIM) + grid RoPE, fp32 [b*S+s][DIM] -> fp16 head-major
// [b][h][s][d]. One block per row.
// ---------------------------------------------------------------------------
__global__ __launch_bounds__(256) void rms_rope_pack_k(
    const float* __restrict__ t, const float* __restrict__ w,
    const float* __restrict__ cf, const float* __restrict__ sf,
    const float* __restrict__ ch, const float* __restrict__ sh,
    const float* __restrict__ cw, const float* __restrict__ sw,
    short* __restrict__ outb)
{
  const int row = blockIdx.x;
  const int b   = row >> 11;
  const int s   = row & (S_ - 1);
  const float* rp = t + (size_t)row * DIM_;

  float ss = 0.f;
  for (int i = threadIdx.x; i < DIM_; i += 256) { float v2 = rp[i]; ss += v2 * v2; }
#pragma unroll
  for (int off = 32; off > 0; off >>= 1) ss += __shfl_down(ss, off);
  __shared__ float red[4];
  if ((threadIdx.x & 63) == 0) red[threadIdx.x >> 6] = ss;
  __syncthreads();
  float scale = rsqrtf((red[0] + red[1] + red[2] + red[3]) * (1.f / DIM_) + 1e-6f);

  const int fi = s >> 8;
  const int hi = (s >> 4) & 15;
  const int wi = s & 15;

  for (int p = threadIdx.x; p < NH_ * 64; p += 256) {
    int n = p >> 6, c = p & 63;
    float co, si;
    if (c < 22)      { co = cf[fi * 22 + c];        si = sf[fi * 22 + c]; }
    else if (c < 43) { co = ch[hi * 21 + (c - 22)]; si = sh[hi * 21 + (c - 22)]; }
    else             { co = cw[wi * 21 + (c - 43)]; si = sw[wi * 21 + (c - 43)]; }
    int d0 = n * HD_ + 2 * c;
    float xr = rp[d0]     * scale * w[d0];
    float xi = rp[d0 + 1] * scale * w[d0 + 1];
    float rr = xr * co - xi * si;
    float ri = xr * si + xi * co;
    unsigned int pk = (unsigned int)(unsigned short)f2h(rr)
                    | ((unsigned int)(unsigned short)f2h(ri) << 16);
    *(unsigned int*)(outb + (((size_t)(b * NH_ + n) * S_ + s) * HD_ + 2 * c)) = pk;
  }
}

// ---------------------------------------------------------------------------
// V transpose: fp32 [b*S+s][h*128+d] -> fp16 [b][h][d][s]
// ---------------------------------------------------------------------------
__global__ __launch_bounds__(256) void v_transpose_k(
    const float* __restrict__ v, short* __restrict__ vtb)
{
  const int bh = blockIdx.y;
  const int b  = bh / NH_;
  const int h  = bh - b * NH_;
  const int s0 = blockIdx.x << 6;
  __shared__ short tile[64][130];
  const int tid = threadIdx.x;
#pragma unroll
  for (int i = 0; i < 8; ++i) {
    int f  = tid + (i << 8);
    int sl = f >> 5, d4 = f & 31;
    float4 t4 = *(const float4*)(v + (size_t)(b * S_ + s0 + sl) * DIM_ + h * 128 + d4 * 4);
    tile[sl][d4 * 4 + 0] = f2h(t4.x);
    tile[sl][d4 * 4 + 1] = f2h(t4.y);
    tile[sl][d4 * 4 + 2] = f2h(t4.z);
    tile[sl][d4 * 4 + 3] = f2h(t4.w);
  }
  __syncthreads();
#pragma unroll
  for (int i = 0; i < 8; ++i) {
    int f  = tid + (i << 8);
    int d  = f >> 4, s4 = f & 15;
    short4v o4;
    o4[0] = tile[s4 * 4 + 0][d];
    o4[1] = tile[s4 * 4 + 1][d];
    o4[2] = tile[s4 * 4 + 2][d];
    o4[3] = tile[s4 * 4 + 3][d];
    *(short4v*)(vtb + ((size_t)bh * HD_ + d) * S_ + s0 + s4 * 4) = o4;
  }
}

// ---------------------------------------------------------------------------
// fp16 MFMA flash attention. Block = 4 waves; wave w owns queries
// q0+16w..+15 of one (b,h). 64-key tiles in swizzled LDS. Writes fp16 att.
// ---------------------------------------------------------------------------
__global__ __launch_bounds__(256) void attn_mfma_k(
    const short* __restrict__ qb, const short* __restrict__ kb,
    const short* __restrict__ vtb, const int* __restrict__ seq_lens,
    short* __restrict__ o16)
{
  const int bh = blockIdx.y;
  const int b  = bh / NH_;
  const int h  = bh - b * NH_;
  const int q0 = blockIdx.x << 6;
  const int kvlen = seq_lens[b];
  const int tid  = threadIdx.x;
  const int wid  = tid >> 6;
  const int lane = tid & 63;
  const int lg   = lane >> 4;
  const int lc   = lane & 15;

  __shared__ __align__(16) short Kt[64 * 128];
  __shared__ __align__(16) short Vt[128 * 64];
  __shared__ __align__(16) short Pt[4][16 * 64];

  f16x8 aq[4];
  {
    const size_t base = ((size_t)bh * S_ + q0 + wid * 16 + lc) * HD_;
#pragma unroll
    for (int kc = 0; kc < 4; ++kc)
      aq[kc] = *reinterpret_cast<const f16x8*>(qb + base + kc * 32 + lg * 8);
  }

  f32x4 oacc[8] = {};
  float mrow[4], lrow[4];
#pragma unroll
  for (int r = 0; r < 4; ++r) { mrow[r] = -3.0e38f; lrow[r] = 0.f; }

  const float c_log2 = 0.08838834764831845f * 1.4426950408889634f;

  char* kbase = (char*)Kt;
  char* vbase = (char*)Vt;
  char* pbase = (char*)(&Pt[wid][0]);

  const int nt = kvlen >> 6;
  for (int t0 = 0; t0 < nt; ++t0) {
    const int k0 = t0 << 6;
    __syncthreads();
#pragma unroll
    for (int i = 0; i < 4; ++i) {
      int c2  = tid + (i << 8);
      int row = c2 >> 4, col = c2 & 15;
      short8v val = *reinterpret_cast<const short8v*>(
          kb + ((size_t)bh * S_ + k0 + row) * HD_ + col * 8);
      *reinterpret_cast<short8v*>(kbase + row * 256 + ((col * 16) ^ ((row & 7) << 4))) = val;
    }
#pragma unroll
    for (int i = 0; i < 4; ++i) {
      int c2  = tid + (i << 8);
      int row = c2 >> 3, col = c2 & 7;
      short8v val = *reinterpret_cast<const short8v*>(
          vtb + ((size_t)bh * HD_ + row) * S_ + k0 + col * 8);
      *reinterpret_cast<short8v*>(vbase + row * 128 + ((col * 16) ^ ((row & 7) << 4))) = val;
    }
    __syncthreads();

    f32x4 sacc[4];
#pragma unroll
    for (int n = 0; n < 4; ++n) {
      f32x4 acc = {0.f, 0.f, 0.f, 0.f};
      int krow = n * 16 + lc;
#pragma unroll
      for (int kc = 0; kc < 4; ++kc) {
        f16x8 bk = *reinterpret_cast<const f16x8*>(
            kbase + krow * 256 + ((kc * 64 + lg * 16) ^ ((krow & 7) << 4)));
        acc = __builtin_amdgcn_mfma_f32_16x16x32_f16(aq[kc], bk, acc, 0, 0, 0);
      }
      sacc[n] = acc;
    }

#pragma unroll
    for (int r = 0; r < 4; ++r) {
      float s0v = sacc[0][r] * c_log2;
      float s1v = sacc[1][r] * c_log2;
      float s2v = sacc[2][r] * c_log2;
      float s3v = sacc[3][r] * c_log2;
      float mx = fmaxf(fmaxf(s0v, s1v), fmaxf(s2v, s3v));
      mx = fmaxf(mx, __shfl_xor(mx, 1));
      mx = fmaxf(mx, __shfl_xor(mx, 2));
      mx = fmaxf(mx, __shfl_xor(mx, 4));
      mx = fmaxf(mx, __shfl_xor(mx, 8));
      float mnew  = fmaxf(mrow[r], mx);
      float alpha = exp2f(mrow[r] - mnew);
      mrow[r] = mnew;
      float p0 = exp2f(s0v - mnew);
      float p1 = exp2f(s1v - mnew);
      float p2 = exp2f(s2v - mnew);
      float p3 = exp2f(s3v - mnew);
      float ls = p0 + p1 + p2 + p3;
      ls += __shfl_xor(ls, 1);
      ls += __shfl_xor(ls, 2);
      ls += __shfl_xor(ls, 4);
      ls += __shfl_xor(ls, 8);
      lrow[r] = lrow[r] * alpha + ls;
#pragma unroll
      for (int n2 = 0; n2 < 8; ++n2) oacc[n2][r] *= alpha;
      int qr = 4 * lg + r;
      int xo = (qr & 7) << 4;
      *(short*)(pbase + qr * 128 + (((0 * 16 + lc) * 2) ^ xo)) = f2h(p0);
      *(short*)(pbase + qr * 128 + (((1 * 16 + lc) * 2) ^ xo)) = f2h(p1);
      *(short*)(pbase + qr * 128 + (((2 * 16 + lc) * 2) ^ xo)) = f2h(p2);
      *(short*)(pbase + qr * 128 + (((3 * 16 + lc) * 2) ^ xo)) = f2h(p3);
    }
    asm volatile("s_waitcnt lgkmcnt(0)" ::: "memory");
    __builtin_amdgcn_sched_barrier(0);

#pragma unroll
    for (int kc2 = 0; kc2 < 2; ++kc2) {
      f16x8 ap = *reinterpret_cast<const f16x8*>(
          pbase + lc * 128 + ((kc2 * 64 + lg * 16) ^ ((lc & 7) << 4)));
#pragma unroll
      for (int n = 0; n < 8; ++n) {
        int vrow = n * 16 + lc;
        f16x8 bv = *reinterpret_cast<const f16x8*>(
            vbase + vrow * 128 + ((kc2 * 64 + lg * 16) ^ ((vrow & 7) << 4)));
        oacc[n] = __builtin_amdgcn_mfma_f32_16x16x32_f16(ap, bv, oacc[n], 0, 0, 0);
      }
    }
  }

  float inv[4];
#pragma unroll
  for (int r = 0; r < 4; ++r) inv[r] = 1.f / lrow[r];
#pragma unroll
  for (int n = 0; n < 8; ++n) {
#pragma unroll
    for (int r = 0; r < 4; ++r) {
      int qrow = q0 + wid * 16 + 4 * lg + r;
      o16[((size_t)(b * S_ + qrow) * NH_ + h) * HD_ + n * 16 + lc] = f2h(oacc[n][r] * inv[r]);
    }
  }
}

// ---------------------------------------------------------------------------
extern "C" void kernel_launch(void* const* d_in, const int* in_sizes, int n_in,
                              void* d_out, int out_size, void* d_ws, size_t ws_size,
                              hipStream_t stream) {
  const float* x        = (const float*)d_in[0];
  const int*   seq_lens = (const int*)d_in[1];
  const float* wq = (const float*)d_in[5];
  const float* bq = (const float*)d_in[6];
  const float* wk = (const float*)d_in[7];
  const float* bk = (const float*)d_in[8];
  const float* wv = (const float*)d_in[9];
  const float* bv = (const float*)d_in[10];
  const float* wo = (const float*)d_in[11];
  const float* bo = (const float*)d_in[12];
  const float* nq = (const float*)d_in[13];
  const float* nk = (const float*)d_in[14];
  const float* cf = (const float*)d_in[15];
  const float* sf = (const float*)d_in[16];
  const float* ch = (const float*)d_in[17];
  const float* sh = (const float*)d_in[18];
  const float* cw = (const float*)d_in[19];
  const float* sw = (const float*)d_in[20];

  const size_t rowelems = (size_t)M_ * DIM_;          // 6291456
  // Workspace plan (88.2 MB total):
  //  A [0..25.2MB):    qf fp32      -> att16 fp16 (after rms_rope(q))
  //  B [25.2..50.4):   kf fp32
  //  C [50.4..75.6):   vf fp32      -> qh fp16 | kh fp16 (after v_transpose)
  //  D [75.6..88.2):   x16 fp16     -> vt fp16 (after qkv GEMMs)
  float* qf  = (float*)d_ws;
  float* kf  = qf + rowelems;
  float* vf  = kf + rowelems;
  short* x16 = (short*)(vf + rowelems);
  short* vt  = x16;                       // reuse after GEMMs
  short* qh  = (short*)vf;                // reuse after v_transpose
  short* kh  = qh + rowelems;
  short* att16 = (short*)qf;              // reuse after rms_rope(q)
  float* out = (float*)d_out;

  f2h_k<<<(int)(rowelems / 8 / 256), 256, 0, stream>>>(x, x16, (int)(rowelems / 8));

  gemm_qkv_k<<<dim3(DIM_ / 128, M_ / 128, 3), 256, 0, stream>>>(
      x16, wq, wk, wv, bq, bk, bv, qf, kf, vf);

  v_transpose_k<<<dim3(S_ / 64, B_ * NH_), 256, 0, stream>>>(vf, vt);

  rms_rope_pack_k<<<M_, 256, 0, stream>>>(qf, nq, cf, sf, ch, sh, cw, sw, qh);
  rms_rope_pack_k<<<M_, 256, 0, stream>>>(kf, nk, cf, sf, ch, sh, cw, sw, kh);

  attn_mfma_k<<<dim3(S_ / 64, B_ * NH_), 256, 0, stream>>>(qh, kh, vt, seq_lens, att16);

  gemm_out_k<<<dim3(DIM_ / 128, M_ / 128), 256, 0, stream>>>(att16, wo, bo, out);
}

// Round 4
// 332.007 us; speedup vs baseline: 9.0280x; 1.3152x over previous
//
#include <hip/hip_runtime.h>
#include <hip/hip_bf16.h>
#include <math.h>

#define DIM_  1536
#define NH_   12
#define HD_   128
#define S_    2048
#define B_    2
#define M_    (B_*S_)   /* 4096 rows */

typedef __attribute__((ext_vector_type(8))) _Float16 f16x8;
typedef __attribute__((ext_vector_type(4))) short short4v;
typedef __attribute__((ext_vector_type(8))) short short8v;
typedef __attribute__((ext_vector_type(4))) float f32x4;

static __device__ __forceinline__ short f2h(float f) {
  union { _Float16 h; short s; } u;
  u.h = (_Float16)f;
  return u.s;
}

// ---------------------------------------------------------------------------
// fp32 -> fp16 pack, 8 elems/thread
// ---------------------------------------------------------------------------
__global__ __launch_bounds__(256) void f2h_k(
    const float* __restrict__ in, short* __restrict__ out, int n8)
{
  int i = blockIdx.x * 256 + threadIdx.x;
  if (i >= n8) return;
  const float4* p = (const float4*)in + (size_t)i * 2;
  float4 a = p[0], b = p[1];
  short8v o;
  o[0] = f2h(a.x); o[1] = f2h(a.y); o[2] = f2h(a.z); o[3] = f2h(a.w);
  o[4] = f2h(b.x); o[5] = f2h(b.y); o[6] = f2h(b.z); o[7] = f2h(b.w);
  *((short8v*)out + i) = o;
}

// ---------------------------------------------------------------------------
// MFMA fp16 GEMM core: Out[4096,1536] = A16[4096,1536] @ W[1536,1536]^T + bias
// 128x128 tile, BK=32, 4 waves (2x2). (unchanged from R2)
// ---------------------------------------------------------------------------
static __device__ __forceinline__ void gemm128_core(
    const short* __restrict__ A16, const float* __restrict__ W,
    const float* __restrict__ bias, float* __restrict__ Out,
    int m0, int n0)
{
  __shared__ __align__(16) char Atile[8192];
  __shared__ __align__(16) char Btile[8192];
  const int tid = threadIdx.x;
  const int l  = tid & 63, w = tid >> 6;
  const int wr = w >> 1, wc = w & 1;
  const int lc = l & 15, lg = l >> 4;

  f32x4 acc[4][4] = {};

  for (int k0 = 0; k0 < DIM_; k0 += 32) {
#pragma unroll
    for (int i = 0; i < 2; ++i) {
      int row   = i * 64 + w * 16 + (l >> 2);
      int slot  = l & 3;
      int gslot = slot ^ ((row >> 1) & 3);
      const short* g = A16 + (size_t)(m0 + row) * DIM_ + k0 + gslot * 8;
      __builtin_amdgcn_global_load_lds(
          (const __attribute__((address_space(1))) unsigned*)g,
          (__attribute__((address_space(3))) unsigned*)(Atile + i * 4096 + w * 1024),
          16, 0, 0);
    }
#pragma unroll
    for (int i = 0; i < 4; ++i) {
      int e   = tid + i * 256;
      int row = e >> 3, f4 = e & 7;
      float4 v4 = *(const float4*)(W + (size_t)(n0 + row) * DIM_ + k0 + f4 * 4);
      short4v h4;
      h4[0] = f2h(v4.x); h4[1] = f2h(v4.y); h4[2] = f2h(v4.z); h4[3] = f2h(v4.w);
      int slot = f4 >> 1;
      *(short4v*)(Btile + row * 64 + (((slot ^ ((row >> 1) & 3)) << 4)) + ((f4 & 1) << 3)) = h4;
    }
    __syncthreads();

    f16x8 af[4], bf[4];
#pragma unroll
    for (int mt = 0; mt < 4; ++mt) {
      int ar = wr * 64 + mt * 16 + lc;
      af[mt] = *(const f16x8*)(Atile + ar * 64 + ((lg ^ ((ar >> 1) & 3)) << 4));
    }
#pragma unroll
    for (int nt = 0; nt < 4; ++nt) {
      int br = wc * 64 + nt * 16 + lc;
      bf[nt] = *(const f16x8*)(Btile + br * 64 + ((lg ^ ((br >> 1) & 3)) << 4));
    }
#pragma unroll
    for (int mt = 0; mt < 4; ++mt)
#pragma unroll
      for (int nt = 0; nt < 4; ++nt)
        acc[mt][nt] = __builtin_amdgcn_mfma_f32_16x16x32_f16(af[mt], bf[nt], acc[mt][nt], 0, 0, 0);
    __syncthreads();
  }

#pragma unroll
  for (int nt = 0; nt < 4; ++nt) {
    int col = n0 + wc * 64 + nt * 16 + lc;
    float bb = bias[col];
#pragma unroll
    for (int mt = 0; mt < 4; ++mt) {
#pragma unroll
      for (int r = 0; r < 4; ++r) {
        int rowm = m0 + wr * 64 + mt * 16 + lg * 4 + r;
        Out[(size_t)rowm * DIM_ + col] = acc[mt][nt][r] + bb;
      }
    }
  }
}

__global__ __launch_bounds__(256) void gemm_qkv_k(
    const short* __restrict__ x16,
    const float* __restrict__ wq, const float* __restrict__ wk, const float* __restrict__ wv,
    const float* __restrict__ bq, const float* __restrict__ bk, const float* __restrict__ bv,
    float* __restrict__ qf, float* __restrict__ kf, float* __restrict__ vf)
{
  const int z = blockIdx.z;
  const float* W  = (z == 0) ? wq : (z == 1) ? wk : wv;
  const float* bi = (z == 0) ? bq : (z == 1) ? bk : bv;
  float*       O  = (z == 0) ? qf : (z == 1) ? kf : vf;
  gemm128_core(x16, W, bi, O, blockIdx.y * 128, blockIdx.x * 128);
}

__global__ __launch_bounds__(256) void gemm_out_k(
    const short* __restrict__ att16, const float* __restrict__ wo,
    const float* __restrict__ bo, float* __restrict__ out)
{
  gemm128_core(att16, wo, bo, out, blockIdx.y * 128, blockIdx.x * 128);
}

// ---------------------------------------------------------------------------
// RMSNorm + grid RoPE -> fp16 head-major [b][h][s][d]. (unchanged)
// ---------------------------------------------------------------------------
__global__ __launch_bounds__(256) void rms_rope_pack_k(
    const float* __restrict__ t, const float* __restrict__ w,
    const float* __restrict__ cf, const float* __restrict__ sf,
    const float* __restrict__ ch, const float* __restrict__ sh,
    const float* __restrict__ cw, const float* __restrict__ sw,
    short* __restrict__ outb)
{
  const int row = blockIdx.x;
  const int b   = row >> 11;
  const int s   = row & (S_ - 1);
  const float* rp = t + (size_t)row * DIM_;

  float ss = 0.f;
  for (int i = threadIdx.x; i < DIM_; i += 256) { float v2 = rp[i]; ss += v2 * v2; }
#pragma unroll
  for (int off = 32; off > 0; off >>= 1) ss += __shfl_down(ss, off);
  __shared__ float red[4];
  if ((threadIdx.x & 63) == 0) red[threadIdx.x >> 6] = ss;
  __syncthreads();
  float scale = rsqrtf((red[0] + red[1] + red[2] + red[3]) * (1.f / DIM_) + 1e-6f);

  const int fi = s >> 8;
  const int hi = (s >> 4) & 15;
  const int wi = s & 15;

  for (int p = threadIdx.x; p < NH_ * 64; p += 256) {
    int n = p >> 6, c = p & 63;
    float co, si;
    if (c < 22)      { co = cf[fi * 22 + c];        si = sf[fi * 22 + c]; }
    else if (c < 43) { co = ch[hi * 21 + (c - 22)]; si = sh[hi * 21 + (c - 22)]; }
    else             { co = cw[wi * 21 + (c - 43)]; si = sw[wi * 21 + (c - 43)]; }
    int d0 = n * HD_ + 2 * c;
    float xr = rp[d0]     * scale * w[d0];
    float xi = rp[d0 + 1] * scale * w[d0 + 1];
    float rr = xr * co - xi * si;
    float ri = xr * si + xi * co;
    unsigned int pk = (unsigned int)(unsigned short)f2h(rr)
                    | ((unsigned int)(unsigned short)f2h(ri) << 16);
    *(unsigned int*)(outb + (((size_t)(b * NH_ + n) * S_ + s) * HD_ + 2 * c)) = pk;
  }
}

// ---------------------------------------------------------------------------
// V transpose: fp32 [b*S+s][h*128+d] -> fp16 [b][h][d][s]. (unchanged)
// ---------------------------------------------------------------------------
__global__ __launch_bounds__(256) void v_transpose_k(
    const float* __restrict__ v, short* __restrict__ vtb)
{
  const int bh = blockIdx.y;
  const int b  = bh / NH_;
  const int h  = bh - b * NH_;
  const int s0 = blockIdx.x << 6;
  __shared__ short tile[64][130];
  const int tid = threadIdx.x;
#pragma unroll
  for (int i = 0; i < 8; ++i) {
    int f  = tid + (i << 8);
    int sl = f >> 5, d4 = f & 31;
    float4 t4 = *(const float4*)(v + (size_t)(b * S_ + s0 + sl) * DIM_ + h * 128 + d4 * 4);
    tile[sl][d4 * 4 + 0] = f2h(t4.x);
    tile[sl][d4 * 4 + 1] = f2h(t4.y);
    tile[sl][d4 * 4 + 2] = f2h(t4.z);
    tile[sl][d4 * 4 + 3] = f2h(t4.w);
  }
  __syncthreads();
#pragma unroll
  for (int i = 0; i < 8; ++i) {
    int f  = tid + (i << 8);
    int d  = f >> 4, s4 = f & 15;
    short4v o4;
    o4[0] = tile[s4 * 4 + 0][d];
    o4[1] = tile[s4 * 4 + 1][d];
    o4[2] = tile[s4 * 4 + 2][d];
    o4[3] = tile[s4 * 4 + 3][d];
    *(short4v*)(vtb + ((size_t)bh * HD_ + d) * S_ + s0 + s4 * 4) = o4;
  }
}

// ---------------------------------------------------------------------------
// fp16 MFMA flash attention v2: swapped QK^T, in-lane softmax, defer-max.
// Block = 2 waves x 32 queries; 64-key tiles; K/V staged via global_load_lds
// (pre-swizzled source, linear LDS dest, swizzled reads).
//   QK:  mfma(A=K[16k x 32d], B=Q[32d x 16q]) -> S^T: col=lc=query, row=4lg+r=key
//   PV:  mfma(A=P[16q x 32k], B=Vt[32k x 16d]) -> O: col=lc=d, row=4lg+r=query
// ---------------------------------------------------------------------------
__global__ __launch_bounds__(128) void attn_mfma2_k(
    const short* __restrict__ qb, const short* __restrict__ kb,
    const short* __restrict__ vtb, const int* __restrict__ seq_lens,
    short* __restrict__ o16)
{
  const int bh = blockIdx.y;
  const int b  = bh / NH_;
  const int h  = bh - b * NH_;
  const int q0 = blockIdx.x << 6;       // 64 queries per block
  const int kvlen = seq_lens[b];
  const int tid  = threadIdx.x;
  const int wid  = tid >> 6;            // 0..1
  const int lane = tid & 63;
  const int lg   = lane >> 4;           // 0..3
  const int lc   = lane & 15;

  __shared__ __align__(16) char Kt[16384];       // [64 keys][128 d] swizzled
  __shared__ __align__(16) char Vt[16384];       // [128 d][64 keys] swizzled
  __shared__ __align__(16) char Pt[2][4096];     // per-wave [32 q][64 k] swizzled

  // Q hoist (B-frag: col=lc=query, k=lg*8+i=d), two 16-q halves per wave
  f16x8 bq0[4], bq1[4];
  {
    const size_t base0 = ((size_t)bh * S_ + q0 + wid * 32 + lc) * HD_;
#pragma unroll
    for (int dc = 0; dc < 4; ++dc) {
      bq0[dc] = *(const f16x8*)(qb + base0 + dc * 32 + lg * 8);
      bq1[dc] = *(const f16x8*)(qb + base0 + 16 * HD_ + dc * 32 + lg * 8);
    }
  }

  f32x4 oacc0[8] = {}, oacc1[8] = {};
  float m0 = -3.0e38f, m1 = -3.0e38f, l0 = 0.f, l1 = 0.f;
  const float c_log2 = 0.08838834764831845f * 1.4426950408889634f;

  const int nt = kvlen >> 6;
  for (int ti = 0; ti < nt; ++ti) {
    const int k0 = ti << 6;
    __syncthreads();   // previous tile's LDS reads complete
    // ---- stage K tile: rows=keys, 256B rows, swizzle folded into source
#pragma unroll
    for (int j = 0; j < 8; ++j) {
      int row = wid * 32 + j * 4 + (lane >> 4);
      const short* g = kb + ((size_t)bh * S_ + k0 + row) * HD_
                          + (((lane & 15) * 8) ^ ((row & 7) << 3));
      __builtin_amdgcn_global_load_lds(
          (const __attribute__((address_space(1))) unsigned*)g,
          (__attribute__((address_space(3))) unsigned*)(Kt + (wid * 32 + j * 4) * 256),
          16, 0, 0);
    }
    // ---- stage V^T tile: rows=d, 128B rows
#pragma unroll
    for (int j = 0; j < 8; ++j) {
      int row = wid * 64 + j * 8 + (lane >> 3);
      const short* g = vtb + ((size_t)bh * HD_ + row) * S_ + k0
                           + (((lane & 7) * 8) ^ ((row & 7) << 3));
      __builtin_amdgcn_global_load_lds(
          (const __attribute__((address_space(1))) unsigned*)g,
          (__attribute__((address_space(3))) unsigned*)(Vt + (wid * 64 + j * 8) * 128),
          16, 0, 0);
    }
    __syncthreads();   // drains vmcnt: tiles ready

    // ---- QK^T (swapped): S^T[key][q]
    f32x4 s0[4], s1[4];
#pragma unroll
    for (int kt = 0; kt < 4; ++kt) {
      f32x4 a0 = {0.f, 0.f, 0.f, 0.f}, a1 = {0.f, 0.f, 0.f, 0.f};
      const int krow = kt * 16 + lc;
      const char* kr = Kt + krow * 256;
      const int xo = (krow & 7) << 4;
#pragma unroll
      for (int dc = 0; dc < 4; ++dc) {
        f16x8 kf = *(const f16x8*)(kr + ((dc * 64 + lg * 16) ^ xo));
        a0 = __builtin_amdgcn_mfma_f32_16x16x32_f16(kf, bq0[dc], a0, 0, 0, 0);
        a1 = __builtin_amdgcn_mfma_f32_16x16x32_f16(kf, bq1[dc], a1, 0, 0, 0);
      }
      s0[kt] = a0; s1[kt] = a1;
    }

    // ---- softmax (lane holds 16 keys for query lc / 16+lc), log2 domain
    float t0 = -3.0e38f, t1 = -3.0e38f;
#pragma unroll
    for (int kt = 0; kt < 4; ++kt)
#pragma unroll
      for (int r = 0; r < 4; ++r) {
        s0[kt][r] *= c_log2; s1[kt][r] *= c_log2;
        t0 = fmaxf(t0, s0[kt][r]); t1 = fmaxf(t1, s1[kt][r]);
      }
    t0 = fmaxf(t0, __shfl_xor(t0, 16)); t0 = fmaxf(t0, __shfl_xor(t0, 32));
    t1 = fmaxf(t1, __shfl_xor(t1, 16)); t1 = fmaxf(t1, __shfl_xor(t1, 32));

    if (__any((t0 > m0 + 8.f) || (t1 > m1 + 8.f))) {   // defer-max rescale
      float mn0 = fmaxf(m0, t0), mn1 = fmaxf(m1, t1);
      float a0 = exp2f(m0 - mn0), a1 = exp2f(m1 - mn1);
      m0 = mn0; m1 = mn1; l0 *= a0; l1 *= a1;
#pragma unroll
      for (int r = 0; r < 4; ++r) {
        float ar0 = __shfl(a0, 4 * lg + r);
        float ar1 = __shfl(a1, 4 * lg + r);
#pragma unroll
        for (int n = 0; n < 8; ++n) { oacc0[n][r] *= ar0; oacc1[n][r] *= ar1; }
      }
    }
    float ls0 = 0.f, ls1 = 0.f;
#pragma unroll
    for (int kt = 0; kt < 4; ++kt)
#pragma unroll
      for (int r = 0; r < 4; ++r) {
        float p0 = exp2f(s0[kt][r] - m0); s0[kt][r] = p0; ls0 += p0;
        float p1 = exp2f(s1[kt][r] - m1); s1[kt][r] = p1; ls1 += p1;
      }
    ls0 += __shfl_xor(ls0, 16); ls0 += __shfl_xor(ls0, 32); l0 += ls0;
    ls1 += __shfl_xor(ls1, 16); ls1 += __shfl_xor(ls1, 32); l1 += ls1;

    // ---- P -> LDS (packed u32 pairs, swizzled); key = kt*16+4*lg+r
    {
      const int xop = (lc & 7) << 4;
      char* pr0 = Pt[wid] + lc * 128;
      char* pr1 = Pt[wid] + (16 + lc) * 128;
#pragma unroll
      for (int kt = 0; kt < 4; ++kt) {
#pragma unroll
        for (int rr = 0; rr < 2; ++rr) {
          unsigned u0 = (unsigned)(unsigned short)f2h(s0[kt][2 * rr])
                      | ((unsigned)(unsigned short)f2h(s0[kt][2 * rr + 1]) << 16);
          unsigned u1 = (unsigned)(unsigned short)f2h(s1[kt][2 * rr])
                      | ((unsigned)(unsigned short)f2h(s1[kt][2 * rr + 1]) << 16);
          int off = (kt * 32 + lg * 8 + rr * 4) ^ xop;
          *(unsigned*)(pr0 + off) = u0;
          *(unsigned*)(pr1 + off) = u1;
        }
      }
    }
    asm volatile("s_waitcnt lgkmcnt(0)" ::: "memory");
    __builtin_amdgcn_sched_barrier(0);

    // ---- PV: O += P @ V
#pragma unroll
    for (int kc = 0; kc < 2; ++kc) {
      const int xop = (lc & 7) << 4;
      f16x8 pa0 = *(const f16x8*)(Pt[wid] + lc * 128 + ((kc * 64 + lg * 16) ^ xop));
      f16x8 pa1 = *(const f16x8*)(Pt[wid] + (16 + lc) * 128 + ((kc * 64 + lg * 16) ^ xop));
#pragma unroll
      for (int n = 0; n < 8; ++n) {
        int vrow = n * 16 + lc;
        f16x8 vf = *(const f16x8*)(Vt + vrow * 128 + ((kc * 64 + lg * 16) ^ ((vrow & 7) << 4)));
        oacc0[n] = __builtin_amdgcn_mfma_f32_16x16x32_f16(pa0, vf, oacc0[n], 0, 0, 0);
        oacc1[n] = __builtin_amdgcn_mfma_f32_16x16x32_f16(pa1, vf, oacc1[n], 0, 0, 0);
      }
    }
  }

  // ---- epilogue: O row=query=4lg+r, col=d=n*16+lc
#pragma unroll
  for (int r = 0; r < 4; ++r) {
    float li0 = 1.f / __shfl(l0, 4 * lg + r);
    float li1 = 1.f / __shfl(l1, 4 * lg + r);
    int qrow0 = q0 + wid * 32 + 4 * lg + r;
#pragma unroll
    for (int n = 0; n < 8; ++n) {
      o16[((size_t)(b * S_ + qrow0) * NH_ + h) * HD_ + n * 16 + lc] = f2h(oacc0[n][r] * li0);
      o16[((size_t)(b * S_ + qrow0 + 16) * NH_ + h) * HD_ + n * 16 + lc] = f2h(oacc1[n][r] * li1);
    }
  }
}

// ---------------------------------------------------------------------------
extern "C" void kernel_launch(void* const* d_in, const int* in_sizes, int n_in,
                              void* d_out, int out_size, void* d_ws, size_t ws_size,
                              hipStream_t stream) {
  const float* x        = (const float*)d_in[0];
  const int*   seq_lens = (const int*)d_in[1];
  const float* wq = (const float*)d_in[5];
  const float* bq = (const float*)d_in[6];
  const float* wk = (const float*)d_in[7];
  const float* bk = (const float*)d_in[8];
  const float* wv = (const float*)d_in[9];
  const float* bv = (const float*)d_in[10];
  const float* wo = (const float*)d_in[11];
  const float* bo = (const float*)d_in[12];
  const float* nq = (const float*)d_in[13];
  const float* nk = (const float*)d_in[14];
  const float* cf = (const float*)d_in[15];
  const float* sf = (const float*)d_in[16];
  const float* ch = (const float*)d_in[17];
  const float* sh = (const float*)d_in[18];
  const float* cw = (const float*)d_in[19];
  const float* sw = (const float*)d_in[20];

  const size_t rowelems = (size_t)M_ * DIM_;          // 6291456
  float* qf  = (float*)d_ws;
  float* kf  = qf + rowelems;
  float* vf  = kf + rowelems;
  short* x16 = (short*)(vf + rowelems);
  short* vt  = x16;                       // reuse after GEMMs
  short* qh  = (short*)vf;                // reuse after v_transpose
  short* kh  = qh + rowelems;
  short* att16 = (short*)qf;              // reuse after rms_rope(q)
  float* out = (float*)d_out;

  f2h_k<<<(int)(rowelems / 8 / 256), 256, 0, stream>>>(x, x16, (int)(rowelems / 8));

  gemm_qkv_k<<<dim3(DIM_ / 128, M_ / 128, 3), 256, 0, stream>>>(
      x16, wq, wk, wv, bq, bk, bv, qf, kf, vf);

  v_transpose_k<<<dim3(S_ / 64, B_ * NH_), 256, 0, stream>>>(vf, vt);

  rms_rope_pack_k<<<M_, 256, 0, stream>>>(qf, nq, cf, sf, ch, sh, cw, sw, qh);
  rms_rope_pack_k<<<M_, 256, 0, stream>>>(kf, nk, cf, sf, ch, sh, cw, sw, kh);

  attn_mfma2_k<<<dim3(S_ / 64, B_ * NH_), 128, 0, stream>>>(qh, kh, vt, seq_lens, att16);

  gemm_out_k<<<dim3(DIM_ / 128, M_ / 128), 256, 0, stream>>>(att16, wo, bo, out);
}

// Round 5
// 321.362 us; speedup vs baseline: 9.3271x; 1.0331x over previous
//
#include <hip/hip_runtime.h>
#include <hip/hip_bf16.h>
#include <math.h>

#define DIM_  1536
#define NH_   12
#define HD_   128
#define S_    2048
#define B_    2
#define M_    (B_*S_)   /* 4096 rows */

typedef __attribute__((ext_vector_type(8))) _Float16 f16x8;
typedef __attribute__((ext_vector_type(4))) short short4v;
typedef __attribute__((ext_vector_type(8))) short short8v;
typedef __attribute__((ext_vector_type(4))) float f32x4;

static __device__ __forceinline__ short f2h(float f) {
  union { _Float16 h; short s; } u;
  u.h = (_Float16)f;
  return u.s;
}

// ---------------------------------------------------------------------------
// fp32 -> fp16 pack, 8 elems/thread
// ---------------------------------------------------------------------------
__global__ __launch_bounds__(256) void f2h_k(
    const float* __restrict__ in, short* __restrict__ out, int n8)
{
  int i = blockIdx.x * 256 + threadIdx.x;
  if (i >= n8) return;
  const float4* p = (const float4*)in + (size_t)i * 2;
  float4 a = p[0], b = p[1];
  short8v o;
  o[0] = f2h(a.x); o[1] = f2h(a.y); o[2] = f2h(a.z); o[3] = f2h(a.w);
  o[4] = f2h(b.x); o[5] = f2h(b.y); o[6] = f2h(b.z); o[7] = f2h(b.w);
  *((short8v*)out + i) = o;
}

// ---------------------------------------------------------------------------
// MFMA fp16 GEMM core: Out[4096,1536] = A16[4096,1536] @ W[1536,1536]^T + bias
// 128x128 tile, BK=32, 4 waves (2x2). (unchanged from R2)
// ---------------------------------------------------------------------------
static __device__ __forceinline__ void gemm128_core(
    const short* __restrict__ A16, const float* __restrict__ W,
    const float* __restrict__ bias, float* __restrict__ Out,
    int m0, int n0)
{
  __shared__ __align__(16) char Atile[8192];
  __shared__ __align__(16) char Btile[8192];
  const int tid = threadIdx.x;
  const int l  = tid & 63, w = tid >> 6;
  const int wr = w >> 1, wc = w & 1;
  const int lc = l & 15, lg = l >> 4;

  f32x4 acc[4][4] = {};

  for (int k0 = 0; k0 < DIM_; k0 += 32) {
#pragma unroll
    for (int i = 0; i < 2; ++i) {
      int row   = i * 64 + w * 16 + (l >> 2);
      int slot  = l & 3;
      int gslot = slot ^ ((row >> 1) & 3);
      const short* g = A16 + (size_t)(m0 + row) * DIM_ + k0 + gslot * 8;
      __builtin_amdgcn_global_load_lds(
          (const __attribute__((address_space(1))) unsigned*)g,
          (__attribute__((address_space(3))) unsigned*)(Atile + i * 4096 + w * 1024),
          16, 0, 0);
    }
#pragma unroll
    for (int i = 0; i < 4; ++i) {
      int e   = tid + i * 256;
      int row = e >> 3, f4 = e & 7;
      float4 v4 = *(const float4*)(W + (size_t)(n0 + row) * DIM_ + k0 + f4 * 4);
      short4v h4;
      h4[0] = f2h(v4.x); h4[1] = f2h(v4.y); h4[2] = f2h(v4.z); h4[3] = f2h(v4.w);
      int slot = f4 >> 1;
      *(short4v*)(Btile + row * 64 + (((slot ^ ((row >> 1) & 3)) << 4)) + ((f4 & 1) << 3)) = h4;
    }
    __syncthreads();

    f16x8 af[4], bf[4];
#pragma unroll
    for (int mt = 0; mt < 4; ++mt) {
      int ar = wr * 64 + mt * 16 + lc;
      af[mt] = *(const f16x8*)(Atile + ar * 64 + ((lg ^ ((ar >> 1) & 3)) << 4));
    }
#pragma unroll
    for (int nt = 0; nt < 4; ++nt) {
      int br = wc * 64 + nt * 16 + lc;
      bf[nt] = *(const f16x8*)(Btile + br * 64 + ((lg ^ ((br >> 1) & 3)) << 4));
    }
#pragma unroll
    for (int mt = 0; mt < 4; ++mt)
#pragma unroll
      for (int nt = 0; nt < 4; ++nt)
        acc[mt][nt] = __builtin_amdgcn_mfma_f32_16x16x32_f16(af[mt], bf[nt], acc[mt][nt], 0, 0, 0);
    __syncthreads();
  }

#pragma unroll
  for (int nt = 0; nt < 4; ++nt) {
    int col = n0 + wc * 64 + nt * 16 + lc;
    float bb = bias[col];
#pragma unroll
    for (int mt = 0; mt < 4; ++mt) {
#pragma unroll
      for (int r = 0; r < 4; ++r) {
        int rowm = m0 + wr * 64 + mt * 16 + lg * 4 + r;
        Out[(size_t)rowm * DIM_ + col] = acc[mt][nt][r] + bb;
      }
    }
  }
}

__global__ __launch_bounds__(256) void gemm_qkv_k(
    const short* __restrict__ x16,
    const float* __restrict__ wq, const float* __restrict__ wk, const float* __restrict__ wv,
    const float* __restrict__ bq, const float* __restrict__ bk, const float* __restrict__ bv,
    float* __restrict__ qf, float* __restrict__ kf, float* __restrict__ vf)
{
  const int z = blockIdx.z;
  const float* W  = (z == 0) ? wq : (z == 1) ? wk : wv;
  const float* bi = (z == 0) ? bq : (z == 1) ? bk : bv;
  float*       O  = (z == 0) ? qf : (z == 1) ? kf : vf;
  gemm128_core(x16, W, bi, O, blockIdx.y * 128, blockIdx.x * 128);
}

__global__ __launch_bounds__(256) void gemm_out_k(
    const short* __restrict__ att16, const float* __restrict__ wo,
    const float* __restrict__ bo, float* __restrict__ out)
{
  gemm128_core(att16, wo, bo, out, blockIdx.y * 128, blockIdx.x * 128);
}

// ---------------------------------------------------------------------------
// RMSNorm + grid RoPE -> fp16 head-major [b][h][s][d]. (unchanged)
// ---------------------------------------------------------------------------
__global__ __launch_bounds__(256) void rms_rope_pack_k(
    const float* __restrict__ t, const float* __restrict__ w,
    const float* __restrict__ cf, const float* __restrict__ sf,
    const float* __restrict__ ch, const float* __restrict__ sh,
    const float* __restrict__ cw, const float* __restrict__ sw,
    short* __restrict__ outb)
{
  const int row = blockIdx.x;
  const int b   = row >> 11;
  const int s   = row & (S_ - 1);
  const float* rp = t + (size_t)row * DIM_;

  float ss = 0.f;
  for (int i = threadIdx.x; i < DIM_; i += 256) { float v2 = rp[i]; ss += v2 * v2; }
#pragma unroll
  for (int off = 32; off > 0; off >>= 1) ss += __shfl_down(ss, off);
  __shared__ float red[4];
  if ((threadIdx.x & 63) == 0) red[threadIdx.x >> 6] = ss;
  __syncthreads();
  float scale = rsqrtf((red[0] + red[1] + red[2] + red[3]) * (1.f / DIM_) + 1e-6f);

  const int fi = s >> 8;
  const int hi = (s >> 4) & 15;
  const int wi = s & 15;

  for (int p = threadIdx.x; p < NH_ * 64; p += 256) {
    int n = p >> 6, c = p & 63;
    float co, si;
    if (c < 22)      { co = cf[fi * 22 + c];        si = sf[fi * 22 + c]; }
    else if (c < 43) { co = ch[hi * 21 + (c - 22)]; si = sh[hi * 21 + (c - 22)]; }
    else             { co = cw[wi * 21 + (c - 43)]; si = sw[wi * 21 + (c - 43)]; }
    int d0 = n * HD_ + 2 * c;
    float xr = rp[d0]     * scale * w[d0];
    float xi = rp[d0 + 1] * scale * w[d0 + 1];
    float rr = xr * co - xi * si;
    float ri = xr * si + xi * co;
    unsigned int pk = (unsigned int)(unsigned short)f2h(rr)
                    | ((unsigned int)(unsigned short)f2h(ri) << 16);
    *(unsigned int*)(outb + (((size_t)(b * NH_ + n) * S_ + s) * HD_ + 2 * c)) = pk;
  }
}

// ---------------------------------------------------------------------------
// V transpose: fp32 [b*S+s][h*128+d] -> fp16 [b][h][d][s]. (unchanged)
// ---------------------------------------------------------------------------
__global__ __launch_bounds__(256) void v_transpose_k(
    const float* __restrict__ v, short* __restrict__ vtb)
{
  const int bh = blockIdx.y;
  const int b  = bh / NH_;
  const int h  = bh - b * NH_;
  const int s0 = blockIdx.x << 6;
  __shared__ short tile[64][130];
  const int tid = threadIdx.x;
#pragma unroll
  for (int i = 0; i < 8; ++i) {
    int f  = tid + (i << 8);
    int sl = f >> 5, d4 = f & 31;
    float4 t4 = *(const float4*)(v + (size_t)(b * S_ + s0 + sl) * DIM_ + h * 128 + d4 * 4);
    tile[sl][d4 * 4 + 0] = f2h(t4.x);
    tile[sl][d4 * 4 + 1] = f2h(t4.y);
    tile[sl][d4 * 4 + 2] = f2h(t4.z);
    tile[sl][d4 * 4 + 3] = f2h(t4.w);
  }
  __syncthreads();
#pragma unroll
  for (int i = 0; i < 8; ++i) {
    int f  = tid + (i << 8);
    int d  = f >> 4, s4 = f & 15;
    short4v o4;
    o4[0] = tile[s4 * 4 + 0][d];
    o4[1] = tile[s4 * 4 + 1][d];
    o4[2] = tile[s4 * 4 + 2][d];
    o4[3] = tile[s4 * 4 + 3][d];
    *(short4v*)(vtb + ((size_t)bh * HD_ + d) * S_ + s0 + s4 * 4) = o4;
  }
}

// ---------------------------------------------------------------------------
// fp16 MFMA flash attention v3: R3 layout + split-barrier pipeline.
// Schedule per 64-key tile:
//   [Kt holds tile t]  issue V(t) loads -> QK(Kt) -> softmax -> P-writes
//   barrier (drains V(t); all Kt reads done)
//   issue K(t+1) loads -> PV(Vt,Pt)
//   barrier (drains K(t+1); all Vt reads done)
// All staging addresses are hoisted pre-swizzled pointers advanced by a
// constant stride per tile.
// ---------------------------------------------------------------------------
__global__ __launch_bounds__(128) void attn_mfma3_k(
    const short* __restrict__ qb, const short* __restrict__ kb,
    const short* __restrict__ vtb, const int* __restrict__ seq_lens,
    short* __restrict__ o16)
{
  const int bh = blockIdx.y;
  const int b  = bh / NH_;
  const int h  = bh - b * NH_;
  const int q0 = blockIdx.x << 6;       // 64 queries per block
  const int kvlen = seq_lens[b];
  const int tid  = threadIdx.x;
  const int wid  = tid >> 6;            // 0..1
  const int lane = tid & 63;
  const int lg   = lane >> 4;           // 0..3
  const int lc   = lane & 15;
  const int xo   = (lc & 7) << 4;       // all fragment-row swizzles (row&7==lc&7)

  __shared__ __align__(16) char Kt[16384];       // [64 keys][128 d] swizzled
  __shared__ __align__(16) char Vt[16384];       // [128 d][64 keys] swizzled
  __shared__ __align__(16) char Pt[2][4096];     // per-wave [32 q][64 k] swizzled

  // ---- Q hoist (B-frag: col=lc=query, k=lg*8+i=d), two 16-q halves per wave
  f16x8 bq0[4], bq1[4];
  {
    const size_t base0 = ((size_t)bh * S_ + q0 + wid * 32 + lc) * HD_;
#pragma unroll
    for (int dc = 0; dc < 4; ++dc) {
      bq0[dc] = *(const f16x8*)(qb + base0 + dc * 32 + lg * 8);
      bq1[dc] = *(const f16x8*)(qb + base0 + 16 * HD_ + dc * 32 + lg * 8);
    }
  }

  // ---- hoisted pre-swizzled staging pointers (advance by const per tile)
  // K rows: wid*32 + j*4 + lg  (row&7 = lg + 4*(j&1))
  const short* kgA = kb + ((size_t)bh * S_ + wid * 32 + lg) * HD_
                        + ((lc * 8) ^ (lg << 3));                       // j even
  const short* kgB = kb + ((size_t)bh * S_ + wid * 32 + 4 + lg) * HD_
                        + ((lc * 8) ^ ((lg ^ 4) << 3));                 // j odd
  // V rows: wid*64 + j*8 + (lane>>3)  (row&7 = lane>>3)
  const short* vg  = vtb + ((size_t)bh * HD_ + wid * 64 + (lane >> 3)) * S_
                         + (((lane & 7) * 8) ^ ((lane >> 3) << 3));

#define STAGE_K()                                                              \
  {                                                                            \
    _Pragma("unroll")                                                          \
    for (int j = 0; j < 8; ++j) {                                              \
      const short* g = (j & 1) ? (kgB + ((j - 1) >> 1) * (8 * HD_))            \
                               : (kgA + (j >> 1) * (8 * HD_));                 \
      __builtin_amdgcn_global_load_lds(                                        \
          (const __attribute__((address_space(1))) unsigned*)g,                \
          (__attribute__((address_space(3))) unsigned*)(Kt + (wid * 32 + j * 4) * 256), \
          16, 0, 0);                                                           \
    }                                                                          \
  }
#define STAGE_V()                                                              \
  {                                                                            \
    _Pragma("unroll")                                                          \
    for (int j = 0; j < 8; ++j) {                                              \
      __builtin_amdgcn_global_load_lds(                                        \
          (const __attribute__((address_space(1))) unsigned*)(vg + j * 8 * S_),\
          (__attribute__((address_space(3))) unsigned*)(Vt + (wid * 64 + j * 8) * 128), \
          16, 0, 0);                                                           \
    }                                                                          \
  }

  f32x4 oacc0[8] = {}, oacc1[8] = {};
  float m0 = -3.0e38f, m1 = -3.0e38f, l0 = 0.f, l1 = 0.f;
  const float c_log2 = 0.08838834764831845f * 1.4426950408889634f;

  const int nt = kvlen >> 6;

  // ---- prologue: stage K(0)
  STAGE_K();
  kgA += 64 * HD_; kgB += 64 * HD_;
  __syncthreads();                 // K(0) ready

  for (int ti = 0; ti < nt; ++ti) {
    // ---- issue V(ti) loads (land during QK+softmax)
    STAGE_V();
    vg += 64;

    // ---- QK^T (swapped): S^T[key][q] from Kt
    f32x4 s0[4], s1[4];
    __builtin_amdgcn_s_setprio(1);
#pragma unroll
    for (int kt = 0; kt < 4; ++kt) {
      f32x4 a0 = {0.f, 0.f, 0.f, 0.f}, a1 = {0.f, 0.f, 0.f, 0.f};
      const char* kr = Kt + (kt * 16 + lc) * 256;
#pragma unroll
      for (int dc = 0; dc < 4; ++dc) {
        f16x8 kf = *(const f16x8*)(kr + ((dc * 64 + lg * 16) ^ xo));
        a0 = __builtin_amdgcn_mfma_f32_16x16x32_f16(kf, bq0[dc], a0, 0, 0, 0);
        a1 = __builtin_amdgcn_mfma_f32_16x16x32_f16(kf, bq1[dc], a1, 0, 0, 0);
      }
      s0[kt] = a0; s1[kt] = a1;
    }
    __builtin_amdgcn_s_setprio(0);

    // ---- softmax (lane holds 16 keys for query lc / 16+lc), log2 domain
    float t0 = -3.0e38f, t1 = -3.0e38f;
#pragma unroll
    for (int kt = 0; kt < 4; ++kt)
#pragma unroll
      for (int r = 0; r < 4; ++r) {
        s0[kt][r] *= c_log2; s1[kt][r] *= c_log2;
        t0 = fmaxf(t0, s0[kt][r]); t1 = fmaxf(t1, s1[kt][r]);
      }
    t0 = fmaxf(t0, __shfl_xor(t0, 16)); t0 = fmaxf(t0, __shfl_xor(t0, 32));
    t1 = fmaxf(t1, __shfl_xor(t1, 16)); t1 = fmaxf(t1, __shfl_xor(t1, 32));

    if (__any((t0 > m0 + 8.f) || (t1 > m1 + 8.f))) {   // defer-max rescale
      float mn0 = fmaxf(m0, t0), mn1 = fmaxf(m1, t1);
      float a0 = exp2f(m0 - mn0), a1 = exp2f(m1 - mn1);
      m0 = mn0; m1 = mn1; l0 *= a0; l1 *= a1;
#pragma unroll
      for (int r = 0; r < 4; ++r) {
        float ar0 = __shfl(a0, 4 * lg + r);
        float ar1 = __shfl(a1, 4 * lg + r);
#pragma unroll
        for (int n = 0; n < 8; ++n) { oacc0[n][r] *= ar0; oacc1[n][r] *= ar1; }
      }
    }
    float ls0 = 0.f, ls1 = 0.f;
#pragma unroll
    for (int kt = 0; kt < 4; ++kt)
#pragma unroll
      for (int r = 0; r < 4; ++r) {
        float p0 = exp2f(s0[kt][r] - m0); s0[kt][r] = p0; ls0 += p0;
        float p1 = exp2f(s1[kt][r] - m1); s1[kt][r] = p1; ls1 += p1;
      }
    ls0 += __shfl_xor(ls0, 16); ls0 += __shfl_xor(ls0, 32); l0 += ls0;
    ls1 += __shfl_xor(ls1, 16); ls1 += __shfl_xor(ls1, 32); l1 += ls1;

    // ---- P -> LDS (packed u32 pairs, swizzled); key = kt*16+4*lg+r
    {
      char* pr0 = Pt[wid] + lc * 128;
      char* pr1 = Pt[wid] + (16 + lc) * 128;
#pragma unroll
      for (int kt = 0; kt < 4; ++kt) {
#pragma unroll
        for (int rr = 0; rr < 2; ++rr) {
          unsigned u0 = (unsigned)(unsigned short)f2h(s0[kt][2 * rr])
                      | ((unsigned)(unsigned short)f2h(s0[kt][2 * rr + 1]) << 16);
          unsigned u1 = (unsigned)(unsigned short)f2h(s1[kt][2 * rr])
                      | ((unsigned)(unsigned short)f2h(s1[kt][2 * rr + 1]) << 16);
          int off = (kt * 32 + lg * 8 + rr * 4) ^ xo;
          *(unsigned*)(pr0 + off) = u0;
          *(unsigned*)(pr1 + off) = u1;
        }
      }
    }

    __syncthreads();               // V(ti) ready (vmcnt drain); Kt reads done

    // ---- issue K(ti+1) loads (land during PV)
    if (ti + 1 < nt) {
      STAGE_K();
      kgA += 64 * HD_; kgB += 64 * HD_;
    }

    // ---- PV: O += P @ V
    __builtin_amdgcn_s_setprio(1);
#pragma unroll
    for (int kc = 0; kc < 2; ++kc) {
      f16x8 pa0 = *(const f16x8*)(Pt[wid] + lc * 128 + ((kc * 64 + lg * 16) ^ xo));
      f16x8 pa1 = *(const f16x8*)(Pt[wid] + (16 + lc) * 128 + ((kc * 64 + lg * 16) ^ xo));
#pragma unroll
      for (int n = 0; n < 8; ++n) {
        f16x8 vf = *(const f16x8*)(Vt + (n * 16 + lc) * 128 + ((kc * 64 + lg * 16) ^ xo));
        oacc0[n] = __builtin_amdgcn_mfma_f32_16x16x32_f16(pa0, vf, oacc0[n], 0, 0, 0);
        oacc1[n] = __builtin_amdgcn_mfma_f32_16x16x32_f16(pa1, vf, oacc1[n], 0, 0, 0);
      }
    }
    __builtin_amdgcn_s_setprio(0);

    __syncthreads();               // K(ti+1) ready; Vt reads done
  }

  // ---- epilogue: O row=query=4lg+r, col=d=n*16+lc
#pragma unroll
  for (int r = 0; r < 4; ++r) {
    float li0 = 1.f / __shfl(l0, 4 * lg + r);
    float li1 = 1.f / __shfl(l1, 4 * lg + r);
    int qrow0 = q0 + wid * 32 + 4 * lg + r;
#pragma unroll
    for (int n = 0; n < 8; ++n) {
      o16[((size_t)(b * S_ + qrow0) * NH_ + h) * HD_ + n * 16 + lc] = f2h(oacc0[n][r] * li0);
      o16[((size_t)(b * S_ + qrow0 + 16) * NH_ + h) * HD_ + n * 16 + lc] = f2h(oacc1[n][r] * li1);
    }
  }
#undef STAGE_K
#undef STAGE_V
}

// ---------------------------------------------------------------------------
extern "C" void kernel_launch(void* const* d_in, const int* in_sizes, int n_in,
                              void* d_out, int out_size, void* d_ws, size_t ws_size,
                              hipStream_t stream) {
  const float* x        = (const float*)d_in[0];
  const int*   seq_lens = (const int*)d_in[1];
  const float* wq = (const float*)d_in[5];
  const float* bq = (const float*)d_in[6];
  const float* wk = (const float*)d_in[7];
  const float* bk = (const float*)d_in[8];
  const float* wv = (const float*)d_in[9];
  const float* bv = (const float*)d_in[10];
  const float* wo = (const float*)d_in[11];
  const float* bo = (const float*)d_in[12];
  const float* nq = (const float*)d_in[13];
  const float* nk = (const float*)d_in[14];
  const float* cf = (const float*)d_in[15];
  const float* sf = (const float*)d_in[16];
  const float* ch = (const float*)d_in[17];
  const float* sh = (const float*)d_in[18];
  const float* cw = (const float*)d_in[19];
  const float* sw = (const float*)d_in[20];

  const size_t rowelems = (size_t)M_ * DIM_;          // 6291456
  float* qf  = (float*)d_ws;
  float* kf  = qf + rowelems;
  float* vf  = kf + rowelems;
  short* x16 = (short*)(vf + rowelems);
  short* vt  = x16;                       // reuse after GEMMs
  short* qh  = (short*)vf;                // reuse after v_transpose
  short* kh  = qh + rowelems;
  short* att16 = (short*)qf;              // reuse after rms_rope(q)
  float* out = (float*)d_out;

  f2h_k<<<(int)(rowelems / 8 / 256), 256, 0, stream>>>(x, x16, (int)(rowelems / 8));

  gemm_qkv_k<<<dim3(DIM_ / 128, M_ / 128, 3), 256, 0, stream>>>(
      x16, wq, wk, wv, bq, bk, bv, qf, kf, vf);

  v_transpose_k<<<dim3(S_ / 64, B_ * NH_), 256, 0, stream>>>(vf, vt);

  rms_rope_pack_k<<<M_, 256, 0, stream>>>(qf, nq, cf, sf, ch, sh, cw, sw, qh);
  rms_rope_pack_k<<<M_, 256, 0, stream>>>(kf, nk, cf, sf, ch, sh, cw, sw, kh);

  attn_mfma3_k<<<dim3(S_ / 64, B_ * NH_), 128, 0, stream>>>(qh, kh, vt, seq_lens, att16);

  gemm_out_k<<<dim3(DIM_ / 128, M_ / 128), 256, 0, stream>>>(att16, wo, bo, out);
}